// Round 8
// baseline (179.054 us; speedup 1.0000x reference)
//
#include <hip/hip_runtime.h>
#include <hip/hip_fp16.h>

// Problem constants: B=2, N=2048, T=8, M=256, D=1024, H=16, HD=64
// rows_x = B*N = 4096, rows_kv = B*T*M = 4096

typedef _Float16 h8 __attribute__((ext_vector_type(8)));
typedef _Float16 h4 __attribute__((ext_vector_type(4)));
typedef float f4 __attribute__((ext_vector_type(4)));

#define DI __device__ __forceinline__

DI void gload16(const void* g, void* l) {
  __builtin_amdgcn_global_load_lds((const __attribute__((address_space(1))) unsigned int*)g,
                                   (__attribute__((address_space(3))) unsigned int*)l, 16, 0, 0);
}

// ---------------- fused prep: LN+cast | media cast | weight transpose | qlist ----------------
// grid: [0,4096) ln rows; [4096,8192) media cast; [8192,9216) transpose (4 x 256 tiles); 9216..9217 qlist
__global__ __launch_bounds__(256) void prep_kernel(
    const float* __restrict__ x, const float* __restrict__ gamma, const float* __restrict__ beta,
    _Float16* __restrict__ xh,
    const float* __restrict__ media, _Float16* __restrict__ kvh,
    const float* __restrict__ W0, const float* __restrict__ W1,
    const float* __restrict__ W2, const float* __restrict__ W3, _Float16* __restrict__ Wt,
    const int* __restrict__ locs, int* __restrict__ cnt, int* __restrict__ qlist) {
  int bid = blockIdx.x;
  int tid = threadIdx.x;
  if (bid < 4096) {
    int row = bid;
    const f4* xr = (const f4*)(x + (size_t)row * 1024);
    f4 v = xr[tid];
    float s = v[0] + v[1] + v[2] + v[3];
    float ss = v[0]*v[0] + v[1]*v[1] + v[2]*v[2] + v[3]*v[3];
    #pragma unroll
    for (int m = 1; m < 64; m <<= 1) { s += __shfl_xor(s, m); ss += __shfl_xor(ss, m); }
    __shared__ float red[8];
    int wid = tid >> 6, lane = tid & 63;
    if (lane == 0) { red[wid] = s; red[4 + wid] = ss; }
    __syncthreads();
    s = red[0] + red[1] + red[2] + red[3];
    ss = red[4] + red[5] + red[6] + red[7];
    float mean = s * (1.0f / 1024.0f);
    float var = ss * (1.0f / 1024.0f) - mean * mean;
    float rs = rsqrtf(var + 1e-5f);
    f4 g = ((const f4*)gamma)[tid], be = ((const f4*)beta)[tid];
    h4 o;
    #pragma unroll
    for (int j = 0; j < 4; ++j) o[j] = (_Float16)((v[j] - mean) * rs * g[j] + be[j]);
    ((h4*)(xh + (size_t)row * 1024))[tid] = o;
  } else if (bid < 8192) {
    int i = (bid - 4096) * 256 + tid;
    f4 v = ((const f4*)media)[i];
    h4 o;
    #pragma unroll
    for (int j = 0; j < 4; ++j) o[j] = (_Float16)v[j];
    ((h4*)kvh)[i] = o;
  } else if (bid < 9216) {
    // ---- weight transpose + cast, 64x64 tiles: Wt[o][i] = W[i][o] ----
    int sec = bid - 8192;
    int z = sec >> 8, r = sec & 255;
    const float* W = z == 0 ? W0 : z == 1 ? W1 : z == 2 ? W2 : W3;
    _Float16* out = Wt + (size_t)z * 1024 * 1024;
    __shared__ float tileF[64][65];
    int i0 = (r & 15) * 64, o0 = (r >> 4) * 64;
    #pragma unroll
    for (int p = 0; p < 4; ++p) {
      int ir = p * 16 + (tid >> 4);
      f4 v = *(const f4*)&W[(size_t)(i0 + ir) * 1024 + o0 + (tid & 15) * 4];
      #pragma unroll
      for (int j = 0; j < 4; ++j) tileF[ir][(tid & 15) * 4 + j] = v[j];
    }
    __syncthreads();
    #pragma unroll
    for (int p = 0; p < 2; ++p) {
      int orow = p * 32 + (tid >> 3);
      h8 v;
      #pragma unroll
      for (int j = 0; j < 8; ++j) v[j] = (_Float16)tileF[(tid & 7) * 8 + j][orow];
      *(h8*)&out[(size_t)(o0 + orow) * 1024 + i0 + (tid & 7) * 8] = v;
    }
  } else {
    int b = bid - 9216;
    __shared__ int lcnt[8];
    if (tid < 8) lcnt[tid] = 0;
    __syncthreads();
    if (tid < 64) {
      int lane = tid;
      int run = 0; int v[32];
      #pragma unroll
      for (int i = 0; i < 32; ++i) { run += locs[b * 2048 + lane * 32 + i]; v[i] = run; }
      int incl = run;
      #pragma unroll
      for (int d = 1; d < 64; d <<= 1) { int t = __shfl_up(incl, d); if (lane >= d) incl += t; }
      int excl = incl - run;
      #pragma unroll
      for (int i = 0; i < 32; ++i) {
        int c = excl + v[i];
        if (c >= 1 && c <= 8) {
          int pos = atomicAdd(&lcnt[c - 1], 1);
          qlist[(b * 8 + (c - 1)) * 2048 + pos] = lane * 32 + i;
        }
      }
    }
    __syncthreads();
    if (tid < 8) cnt[b * 8 + tid] = lcnt[tid];
  }
}

struct GemmDesc { const _Float16* A; const _Float16* Bt; const float* bias; void* C; int mode; };
struct GemmBatch { GemmDesc d[3]; };

// ---------------- fp16 MFMA GEMM, 128x128 tile, BK=64, 4 waves of 64x64 ----------------
// LDS reads/block-step: 64 (was 96 with 8 waves of 64x32) — LDS port was the measured
// bottleneck (~23us/CU of b128 reads at the 8-wave shape). MFMA count unchanged.
// mode 0: C fp16 [.][1024];  mode 2: V transposed-per-head store: Vt[(b*16+h)*64+d][s], ld=2048
__global__ __launch_bounds__(256, 3) void gemm128(GemmBatch gb) {
  GemmDesc g = gb.d[blockIdx.z];
  // XCD-aware swizzle within z-slice (256 blocks, 8 XCDs, cpx=32)
  int id = blockIdx.y * 8 + blockIdx.x;
  int id2 = (id & 7) * 32 + (id >> 3);
  int row0 = (id2 >> 3) * 128, col0 = (id2 & 7) * 128;
  __shared__ alignas(16) _Float16 As[128 * 64];
  __shared__ alignas(16) _Float16 Bs[128 * 64];
  int tid = threadIdx.x, lane = tid & 63, wid = tid >> 6;
  int wr = wid >> 1, wc = wid & 1;           // wave -> 64-row group x 64-col group
  f4 acc[4][4] = {};
  // staging: pass p covers rows p*32 + (tid>>3), chunk tid&7; source chunk pre-swizzled
  int rs = tid >> 3, cs = tid & 7;
  const _Float16* gA[4]; const _Float16* gB[4];
  #pragma unroll
  for (int p = 0; p < 4; ++p) {
    int rp = p * 32 + rs;
    int cg = cs ^ (rp & 7);
    gA[p] = g.A  + (size_t)(row0 + rp) * 1024 + cg * 8;
    gB[p] = g.Bt + (size_t)(col0 + rp) * 1024 + cg * 8;
  }
  #pragma unroll 1
  for (int kt = 0; kt < 16; ++kt) {
    __syncthreads();
    #pragma unroll
    for (int p = 0; p < 4; ++p) {
      gload16(gA[p] + kt * 64, (void*)&As[p * 2048 + wid * 512]);
      gload16(gB[p] + kt * 64, (void*)&Bs[p * 2048 + wid * 512]);
    }
    __syncthreads();
    #pragma unroll
    for (int kk = 0; kk < 2; ++kk) {
      h8 af[4], bf[4];
      #pragma unroll
      for (int m = 0; m < 4; ++m) {
        int r = wr * 64 + m * 16 + (lane & 15);
        int c = ((lane >> 4) + kk * 4) ^ (r & 7);
        af[m] = *(const h8*)&As[r * 64 + c * 8];
      }
      #pragma unroll
      for (int n = 0; n < 4; ++n) {
        int r = wc * 64 + n * 16 + (lane & 15);
        int c = ((lane >> 4) + kk * 4) ^ (r & 7);
        bf[n] = *(const h8*)&Bs[r * 64 + c * 8];
      }
      #pragma unroll
      for (int m = 0; m < 4; ++m)
        #pragma unroll
        for (int n = 0; n < 4; ++n)
          acc[m][n] = __builtin_amdgcn_mfma_f32_16x16x32_f16(af[m], bf[n], acc[m][n], 0, 0, 0);
    }
  }
  int colb = col0 + wc * 64;
  float bias_v[4];
  #pragma unroll
  for (int n = 0; n < 4; ++n) bias_v[n] = g.bias[colb + n * 16 + (lane & 15)];
  #pragma unroll
  for (int m = 0; m < 4; ++m) {
    int row = row0 + wr * 64 + m * 16 + (lane >> 4) * 4;
    #pragma unroll
    for (int n = 0; n < 4; ++n) {
      int col = colb + n * 16 + (lane & 15);
      if (g.mode == 0) {
        _Float16* C = (_Float16*)g.C;
        #pragma unroll
        for (int j = 0; j < 4; ++j)
          C[(size_t)(row + j) * 1024 + col] = (_Float16)(acc[m][n][j] + bias_v[n]);
      } else {
        _Float16* C = (_Float16*)g.C;
        h4 pk;
        #pragma unroll
        for (int j = 0; j < 4; ++j) pk[j] = (_Float16)(acc[m][n][j] + bias_v[n]);
        size_t vrow = (size_t)((row >> 11) * 1024 + col);   // (b*16+h)*64+d == b*1024+col
        *(h4*)&C[vrow * 2048 + (row & 2047)] = pk;
      }
    }
  }
}

// ---------------- out-projection GEMM: 64x128 tile, BK=64, 512 blocks (2/CU) ----------------
__global__ __launch_bounds__(512) void gemm_out(const _Float16* __restrict__ A,
    const _Float16* __restrict__ Bt, const float* __restrict__ bias, float* __restrict__ C) {
  int id = blockIdx.y * 8 + blockIdx.x;
  int id2 = (id & 7) * 64 + (id >> 3);
  int row0 = (id2 >> 3) * 64, col0 = (id2 & 7) * 128;
  __shared__ alignas(16) _Float16 As[64 * 64];
  __shared__ alignas(16) _Float16 Bs[128 * 64];
  int tid = threadIdx.x, lane = tid & 63, wid = tid >> 6;
  int wr = wid >> 2, wc = wid & 3;   // wave: 32 rows x 32 cols
  f4 acc[2][2] = {};
  int rs = tid >> 3, c0s = tid & 7;
  int cg = c0s ^ (rs & 7);
  const _Float16* gA  = A  + (size_t)(row0 + rs) * 1024 + cg * 8;
  const _Float16* gB0 = Bt + (size_t)(col0 + rs) * 1024 + cg * 8;
  const _Float16* gB1 = gB0 + (size_t)64 * 1024;
  #pragma unroll 1
  for (int kt = 0; kt < 16; ++kt) {
    __syncthreads();
    gload16(gA  + kt * 64, (void*)&As[wid * 512]);
    gload16(gB0 + kt * 64, (void*)&Bs[wid * 512]);
    gload16(gB1 + kt * 64, (void*)&Bs[4096 + wid * 512]);
    __syncthreads();
    #pragma unroll
    for (int kk = 0; kk < 2; ++kk) {
      h8 a[2], b[2];
      #pragma unroll
      for (int m = 0; m < 2; ++m) {
        int r = wr * 32 + m * 16 + (lane & 15);
        int c = ((lane >> 4) + kk * 4) ^ (r & 7);
        a[m] = *(const h8*)&As[r * 64 + c * 8];
      }
      #pragma unroll
      for (int n = 0; n < 2; ++n) {
        int r = wc * 32 + n * 16 + (lane & 15);
        int c = ((lane >> 4) + kk * 4) ^ (r & 7);
        b[n] = *(const h8*)&Bs[r * 64 + c * 8];
      }
      #pragma unroll
      for (int m = 0; m < 2; ++m)
        #pragma unroll
        for (int n = 0; n < 2; ++n)
          acc[m][n] = __builtin_amdgcn_mfma_f32_16x16x32_f16(a[m], b[n], acc[m][n], 0, 0, 0);
    }
  }
  int colb = col0 + wc * 32;
  float bias_v[2];
  #pragma unroll
  for (int n = 0; n < 2; ++n) bias_v[n] = bias[colb + n * 16 + (lane & 15)];
  #pragma unroll
  for (int m = 0; m < 2; ++m) {
    int row = row0 + wr * 32 + m * 16 + (lane >> 4) * 4;
    #pragma unroll
    for (int n = 0; n < 2; ++n) {
      int col = colb + n * 16 + (lane & 15);
      #pragma unroll
      for (int j = 0; j < 4; ++j)
        C[(size_t)(row + j) * 1024 + col] = acc[m][n][j] + bias_v[n];
    }
  }
}

// ---------------- masked cross-attention ----------------
__global__ __launch_bounds__(512) void attn_kernel(const _Float16* __restrict__ Qg,
    const _Float16* __restrict__ Kg, const _Float16* __restrict__ Vtg,
    const int* __restrict__ cnt, const int* __restrict__ qlist, _Float16* __restrict__ Og) {
  int h = blockIdx.x, f = blockIdx.y, b = blockIdx.z;
  __shared__ alignas(16) _Float16 Kl[256 * 64];
  __shared__ alignas(16) _Float16 Vl[64 * 256];
  __shared__ alignas(16) _Float16 Sl[8 * 16 * 256];
  int tid = threadIdx.x;
  for (int idx = tid; idx < 2048; idx += 512) {
    int r = idx >> 3, c = idx & 7;
    h8 v = *(const h8*)&Kg[((size_t)(b * 2048 + f * 256 + r)) * 1024 + h * 64 + c * 8];
    *(h8*)&Kl[r * 64 + ((c ^ (r & 7)) * 8)] = v;
  }
  for (int idx = tid; idx < 2048; idx += 512) {
    int d = idx >> 5, cc = idx & 31;
    h8 v = *(const h8*)&Vtg[((size_t)(b * 1024 + h * 64 + d)) * 2048 + f * 256 + cc * 8];
    *(h8*)&Vl[d * 256 + ((cc ^ (d & 7)) * 8)] = v;
  }
  __syncthreads();
  int nq = cnt[b * 8 + f];
  int lane = tid & 63, wid = tid >> 6;
  const int* ql = qlist + (b * 8 + f) * 2048;
  _Float16* Sw = &Sl[wid * 4096];
  for (int st = wid; st * 16 < nq; st += 8) {
    int qbase = st * 16;
    int nv = nq - qbase; if (nv > 16) nv = 16;
    int li = lane & 15; if (li > nv - 1) li = nv - 1;
    int qrow = b * 2048 + ql[qbase + li];
    h8 aq0 = *(const h8*)&Qg[(size_t)qrow * 1024 + h * 64 + (lane >> 4) * 8];
    h8 aq1 = *(const h8*)&Qg[(size_t)qrow * 1024 + h * 64 + 32 + (lane >> 4) * 8];
    f4 s[16];
    #pragma unroll
    for (int kt = 0; kt < 16; ++kt) {
      int key = kt * 16 + (lane & 15);
      int cb0 = lane >> 4;
      h8 bk0 = *(const h8*)&Kl[key * 64 + ((cb0 ^ (key & 7)) * 8)];
      h8 bk1 = *(const h8*)&Kl[key * 64 + (((cb0 + 4) ^ (key & 7)) * 8)];
      f4 z = {0.f, 0.f, 0.f, 0.f};
      s[kt] = __builtin_amdgcn_mfma_f32_16x16x32_f16(aq0, bk0, z, 0, 0, 0);
      s[kt] = __builtin_amdgcn_mfma_f32_16x16x32_f16(aq1, bk1, s[kt], 0, 0, 0);
    }
    float mx[4], sm[4];
    #pragma unroll
    for (int j = 0; j < 4; ++j) {
      float m = s[0][j];
      #pragma unroll
      for (int kt = 1; kt < 16; ++kt) m = fmaxf(m, s[kt][j]);
      #pragma unroll
      for (int d = 1; d < 16; d <<= 1) m = fmaxf(m, __shfl_xor(m, d));
      mx[j] = m; sm[j] = 0.f;
    }
    #pragma unroll
    for (int kt = 0; kt < 16; ++kt) {
      int keyb = kt * 16 + (lane & 15);
      int cbk = keyb >> 3, wi = keyb & 7;
      #pragma unroll
      for (int j = 0; j < 4; ++j) {
        float p = __expf((s[kt][j] - mx[j]) * 0.125f);
        sm[j] += p;
        int q = (lane >> 4) * 4 + j;
        Sw[q * 256 + ((cbk ^ (q & 7)) * 8) + wi] = (_Float16)p;
      }
    }
    #pragma unroll
    for (int j = 0; j < 4; ++j) {
      float x = sm[j];
      #pragma unroll
      for (int d = 1; d < 16; d <<= 1) x += __shfl_xor(x, d);
      sm[j] = x;
    }
    f4 o[4] = {};
    #pragma unroll
    for (int c32 = 0; c32 < 8; ++c32) {
      int qa = lane & 15;
      int cba = c32 * 4 + (lane >> 4);
      h8 pa = *(const h8*)&Sw[qa * 256 + ((cba ^ (qa & 7)) * 8)];
      #pragma unroll
      for (int dt = 0; dt < 4; ++dt) {
        int dd = dt * 16 + (lane & 15);
        h8 bv_ = *(const h8*)&Vl[dd * 256 + ((cba ^ (dd & 7)) * 8)];
        o[dt] = __builtin_amdgcn_mfma_f32_16x16x32_f16(pa, bv_, o[dt], 0, 0, 0);
      }
    }
    #pragma unroll
    for (int j = 0; j < 4; ++j) {
      int q = (lane >> 4) * 4 + j;
      if (q < nv) {
        int qr = __shfl(qrow, q);
        float inv = 1.0f / sm[j];
        #pragma unroll
        for (int dt = 0; dt < 4; ++dt)
          Og[(size_t)qr * 1024 + h * 64 + dt * 16 + (lane & 15)] = (_Float16)(o[dt][j] * inv);
      }
    }
  }
}

// ---------------- launch ----------------
extern "C" void kernel_launch(void* const* d_in, const int* in_sizes, int n_in,
                              void* d_out, int out_size, void* d_ws, size_t ws_size,
                              hipStream_t stream) {
  const float* text  = (const float*)d_in[0];
  const float* media = (const float*)d_in[1];
  const int*   locs  = (const int*)d_in[2];
  const float* gamma = (const float*)d_in[3];
  const float* beta  = (const float*)d_in[4];
  const float* wq = (const float*)d_in[5];
  const float* wk = (const float*)d_in[6];
  const float* wv = (const float*)d_in[7];
  const float* bq = (const float*)d_in[8];
  const float* bk = (const float*)d_in[9];
  const float* bv = (const float*)d_in[10];
  const float* wo = (const float*)d_in[11];
  const float* bo = (const float*)d_in[12];

  char* ws = (char*)d_ws;
  size_t off = 0;
  auto take = [&](size_t bytes) { void* p = ws + off; off += (bytes + 255) & ~(size_t)255; return p; };
  _Float16* xh  = (_Float16*)take((size_t)4096 * 1024 * 2);
  _Float16* kvh = (_Float16*)take((size_t)4096 * 1024 * 2);
  _Float16* wt  = (_Float16*)take((size_t)4 * 1024 * 1024 * 2);
  _Float16* Qm  = (_Float16*)take((size_t)4096 * 1024 * 2);
  _Float16* Km  = (_Float16*)take((size_t)4096 * 1024 * 2);
  _Float16* Vt  = (_Float16*)take((size_t)2048 * 2048 * 2);
  _Float16* Om  = (_Float16*)take((size_t)4096 * 1024 * 2);
  int* cnt   = (int*)take(64 * sizeof(int));
  int* qlist = (int*)take((size_t)2 * 8 * 2048 * sizeof(int));

  prep_kernel<<<9218, 256, 0, stream>>>(text, gamma, beta, xh, media, kvh,
                                        wq, wk, wv, wo, wt, locs, cnt, qlist);

  GemmBatch gb;
  gb.d[0] = { xh,  wt,                       bq, (void*)Qm, 0 };
  gb.d[1] = { kvh, wt + (size_t)1 * 1048576, bk, (void*)Km, 0 };
  gb.d[2] = { kvh, wt + (size_t)2 * 1048576, bv, (void*)Vt, 2 };
  gemm128<<<dim3(8, 32, 3), 256, 0, stream>>>(gb);

  attn_kernel<<<dim3(16, 8, 2), 512, 0, stream>>>(Qm, Km, Vt, cnt, qlist, Om);

  gemm_out<<<dim3(8, 64), 512, 0, stream>>>(Om, wt + (size_t)3 * 1048576, bo, (float*)d_out);
}